// Round 1
// baseline (4254.218 us; speedup 1.0000x reference)
//
#include <hip/hip_runtime.h>

typedef unsigned short ushort_t;
typedef unsigned int uint_t;

#define N_NODES 65536
#define N_EDGES 262144

// ---------- bf16 helpers ----------
__device__ __forceinline__ ushort_t f2b(float x) {
  uint_t u = __float_as_uint(x);
  u += 0x7fffu + ((u >> 16) & 1u);   // round-to-nearest-even
  return (ushort_t)(u >> 16);
}
__device__ __forceinline__ void dec8(uint4 v, float* f) {
  f[0] = __uint_as_float(v.x << 16); f[1] = __uint_as_float(v.x & 0xffff0000u);
  f[2] = __uint_as_float(v.y << 16); f[3] = __uint_as_float(v.y & 0xffff0000u);
  f[4] = __uint_as_float(v.z << 16); f[5] = __uint_as_float(v.z & 0xffff0000u);
  f[6] = __uint_as_float(v.w << 16); f[7] = __uint_as_float(v.w & 0xffff0000u);
}
__device__ __forceinline__ void dec4(uint2 v, float* f) {
  f[0] = __uint_as_float(v.x << 16); f[1] = __uint_as_float(v.x & 0xffff0000u);
  f[2] = __uint_as_float(v.y << 16); f[3] = __uint_as_float(v.y & 0xffff0000u);
}
__device__ __forceinline__ uint4 enc8(const float* f) {
  uint4 v;
  v.x = (uint_t)f2b(f[0]) | ((uint_t)f2b(f[1]) << 16);
  v.y = (uint_t)f2b(f[2]) | ((uint_t)f2b(f[3]) << 16);
  v.z = (uint_t)f2b(f[4]) | ((uint_t)f2b(f[5]) << 16);
  v.w = (uint_t)f2b(f[6]) | ((uint_t)f2b(f[7]) << 16);
  return v;
}
__device__ __forceinline__ uint2 enc4(const float* f) {
  uint2 v;
  v.x = (uint_t)f2b(f[0]) | ((uint_t)f2b(f[1]) << 16);
  v.y = (uint_t)f2b(f[2]) | ((uint_t)f2b(f[3]) << 16);
  return v;
}
__device__ __forceinline__ void ld8(const float* p, float* f) {
  float4 v0 = *(const float4*)p;
  float4 v1 = *(const float4*)(p + 4);
  f[0]=v0.x; f[1]=v0.y; f[2]=v0.z; f[3]=v0.w;
  f[4]=v1.x; f[5]=v1.y; f[6]=v1.z; f[7]=v1.w;
}

// ---------- shared-tile helpers (32-wide K chunk, 16B-slot rotation) ----------
// sWt[c][k] staged transposed from W[h][d][p] ([4][256][64] f32), chunk d=dc*32..+31
__device__ __forceinline__ void stage_w_hd(const float* __restrict__ W, int dc,
                                           float (*sWt)[32], int t) {
#pragma unroll
  for (int i = 0; i < 4; ++i) {
    int idx = i * 256 + t;          // 0..1023
    int hd = idx >> 3, seg = idx & 7;
    int hh = hd >> 5, dl = hd & 31;
    const float* src = W + (((long)(hh * 256 + dc * 32 + dl)) << 6) + seg * 8;
    float f[8]; ld8(src, f);
    int sl = dl >> 2, ke = dl & 3;
#pragma unroll
    for (int j = 0; j < 8; ++j) {
      int c = (hh << 6) + seg * 8 + j;
      sWt[c][(((sl + ((c >> 3) & 7)) & 7) << 2) + ke] = f[j];
    }
  }
}
// sWt staged from row-major W[K][256] f32, chunk k=kb..kb+31
__device__ __forceinline__ void stage_w_km(const float* __restrict__ W, int kb,
                                           float (*sWt)[32], int t) {
#pragma unroll
  for (int i = 0; i < 4; ++i) {
    int idx = i * 256 + t;
    int k = idx >> 5, cs = (idx & 31) * 8;
    const float* src = W + (long)(kb + k) * 256 + cs;
    float f[8]; ld8(src, f);
    int sl = k >> 2, ke = k & 3;
#pragma unroll
    for (int j = 0; j < 8; ++j) {
      int c = cs + j;
      sWt[c][(((sl + ((c >> 3) & 7)) & 7) << 2) + ke] = f[j];
    }
  }
}
__device__ __forceinline__ void read_w8(const float (*sWt)[32], int tc, int s8,
                                        float w[8][8]) {
#pragma unroll
  for (int i = 0; i < 8; ++i) {
    int c = tc * 8 + i;
    int rot = (c >> 3) & 7;
    float4 lo = *(const float4*)&sWt[c][((2 * s8 + rot) & 7) << 2];
    float4 hi = *(const float4*)&sWt[c][((2 * s8 + 1 + rot) & 7) << 2];
    w[i][0]=lo.x; w[i][1]=lo.y; w[i][2]=lo.z; w[i][3]=lo.w;
    w[i][4]=hi.x; w[i][5]=hi.y; w[i][6]=hi.z; w[i][7]=hi.w;
  }
}
__device__ __forceinline__ void read_a8(const float (*sA)[32], int row, int rot, int s8,
                                        float* a) {
  float4 lo = *(const float4*)&sA[row][((2 * s8 + rot) & 7) << 2];
  float4 hi = *(const float4*)&sA[row][((2 * s8 + 1 + rot) & 7) << 2];
  a[0]=lo.x; a[1]=lo.y; a[2]=lo.z; a[3]=lo.w;
  a[4]=hi.x; a[5]=hi.y; a[6]=hi.z; a[7]=hi.w;
}

// ---------- generic GEMM: out[rows][256] = A[rows][K] @ W[K][256] ----------
template <bool BF16OUT>
__global__ __launch_bounds__(256, 2) void gemm_k(
    const float* __restrict__ A, const float* __restrict__ W,
    void* __restrict__ outv, int K) {
  __shared__ __align__(16) float sA[64][32];
  __shared__ __align__(16) float sWt[256][32];
  int t = threadIdx.x;
  long r0 = (long)blockIdx.x * 64;
  int tc = t & 31, te = t >> 5;
  float acc[8][8];
#pragma unroll
  for (int r = 0; r < 8; ++r)
#pragma unroll
    for (int i = 0; i < 8; ++i) acc[r][i] = 0.f;

  for (int kb = 0; kb < K; kb += 32) {
    __syncthreads();
    {  // stage A chunk (f32)
      int row = t >> 2, s = t & 3;
      const float* src = A + (r0 + row) * (long)K + kb + s * 8;
      float4 v0 = *(const float4*)src;
      float4 v1 = *(const float4*)(src + 4);
      int rot = (row >> 3) & 7;
      *(float4*)&sA[row][((2 * s + rot) & 7) << 2] = v0;
      *(float4*)&sA[row][((2 * s + 1 + rot) & 7) << 2] = v1;
    }
    stage_w_km(W, kb, sWt, t);
    __syncthreads();
    for (int s8 = 0; s8 < 4; ++s8) {
      float w[8][8];
      read_w8(sWt, tc, s8, w);
#pragma unroll
      for (int r = 0; r < 8; ++r) {
        float a[8];
        read_a8(sA, te * 8 + r, te & 7, s8, a);
#pragma unroll
        for (int i = 0; i < 8; ++i)
#pragma unroll
          for (int d = 0; d < 8; ++d) acc[r][i] += a[d] * w[i][d];
      }
    }
  }
#pragma unroll
  for (int r = 0; r < 8; ++r) {
    long row = r0 + te * 8 + r;
    if (BF16OUT) {
      float f[8];
#pragma unroll
      for (int i = 0; i < 8; ++i) f[i] = acc[r][i];
      *(uint4*)((ushort_t*)outv + row * 256 + tc * 8) = enc8(f);
    } else {
      float* o = (float*)outv + row * 256 + tc * 8;
      *(float4*)o = make_float4(acc[r][0], acc[r][1], acc[r][2], acc[r][3]);
      *(float4*)(o + 4) = make_float4(acc[r][4], acc[r][5], acc[r][6], acc[r][7]);
    }
  }
}

// ---------- edge aggregator (runs only at L=0; x = base, lda 256) ----------
__global__ __launch_bounds__(256, 2) void edge_kernel(
    const float* __restrict__ xf, const ushort_t* __restrict__ ein,
    ushort_t* __restrict__ eout, const int* __restrict__ ena,
    const float* __restrict__ a_n, const float* __restrict__ a_e,
    const float* __restrict__ We) {
  __shared__ int sIdx[64][2];
  __shared__ float sAlp[64][4][2];
  __shared__ __align__(16) ushort_t sY[4][64][32];
  __shared__ __align__(16) float sWt[256][32];
  int t = threadIdx.x;
  long e0g = (long)blockIdx.x * 64;

  if (t < 128) ((int*)sIdx)[t] = ena[e0g * 2 + t];
  __syncthreads();

  {  // phase 1: attention scores, 4 threads per edge
    int e = t >> 2, q = t & 3;
    const ushort_t* pe = ein + (e0g + e) * 256 + q * 64;
    const float* p0 = xf + (long)sIdx[e][0] * 256 + q * 64;
    const float* p1 = xf + (long)sIdx[e][1] * 256 + q * 64;
    float an0[4] = {0,0,0,0}, an1[4] = {0,0,0,0}, aee[4] = {0,0,0,0};
#pragma unroll
    for (int j = 0; j < 8; ++j) {
      int dof = q * 64 + j * 8;
      float xe[8], x0[8], x1[8];
      dec8(*(const uint4*)(pe + j * 8), xe);
      ld8(p0 + j * 8, x0);
      ld8(p1 + j * 8, x1);
#pragma unroll
      for (int h = 0; h < 4; ++h) {
        float av[8], bv[8];
        ld8(a_n + h * 256 + dof, av);
        ld8(a_e + h * 256 + dof, bv);
#pragma unroll
        for (int d = 0; d < 8; ++d) {
          an0[h] += x0[d] * av[d];
          an1[h] += x1[d] * av[d];
          aee[h] += xe[d] * bv[d];
        }
      }
    }
#pragma unroll
    for (int m = 1; m <= 2; m <<= 1)
#pragma unroll
      for (int h = 0; h < 4; ++h) {
        an0[h] += __shfl_xor(an0[h], m, 64);
        an1[h] += __shfl_xor(an1[h], m, 64);
        aee[h] += __shfl_xor(aee[h], m, 64);
      }
    if (q == 0) {
#pragma unroll
      for (int h = 0; h < 4; ++h) {
        float s0 = an0[h] + aee[h]; s0 = s0 > 0.f ? s0 : 0.2f * s0;
        float s1 = an1[h] + aee[h]; s1 = s1 > 0.f ? s1 : 0.2f * s1;
        float mx = fmaxf(s0, s1);
        float g0 = __expf(s0 - mx), g1 = __expf(s1 - mx);
        float inv = 1.f / (g0 + g1);
        sAlp[e][h][0] = g0 * inv;
        sAlp[e][h][1] = g1 * inv;
      }
    }
  }
  __syncthreads();

  // phase 2: projection. 8 edges x 8 cols per thread.
  int tc = t & 31, te = t >> 5;
  int hT = tc >> 3;
  int eL = t >> 2, sL = t & 3;  // sY-build task assignment
  const ushort_t* peB = ein + (e0g + eL) * 256;
  const float* p0B = xf + (long)sIdx[eL][0] * 256;
  const float* p1B = xf + (long)sIdx[eL][1] * 256;
  float alpB[4][2];
#pragma unroll
  for (int h = 0; h < 4; ++h) {
    alpB[h][0] = sAlp[eL][h][0];
    alpB[h][1] = sAlp[eL][h][1];
  }
  float acc[8][8];
#pragma unroll
  for (int r = 0; r < 8; ++r)
#pragma unroll
    for (int i = 0; i < 8; ++i) acc[r][i] = 0.f;

  for (int dc = 0; dc < 8; ++dc) {
    __syncthreads();
    {  // build Y = edges + alp0*ep0 + alp1*ep1, per head, bf16 into sY
      int doff = dc * 32 + sL * 8;
      float xe[8], x0[8], x1[8];
      dec8(*(const uint4*)(peB + doff), xe);
      ld8(p0B + doff, x0);
      ld8(p1B + doff, x1);
      int phys = ((sL + ((eL >> 3) & 3)) & 3) << 3;
#pragma unroll
      for (int h = 0; h < 4; ++h) {
        float y[8];
#pragma unroll
        for (int d = 0; d < 8; ++d)
          y[d] = xe[d] + alpB[h][0] * x0[d] + alpB[h][1] * x1[d];
        *(uint4*)&sY[h][eL][phys] = enc8(y);
      }
    }
    stage_w_hd(We, dc, sWt, t);
    __syncthreads();
    for (int s8 = 0; s8 < 4; ++s8) {
      float w[8][8];
      read_w8(sWt, tc, s8, w);
#pragma unroll
      for (int r = 0; r < 8; ++r) {
        int row = te * 8 + r;
        float a[8];
        dec8(*(const uint4*)&sY[hT][row][(((s8 + (te & 3)) & 3) << 3)], a);
#pragma unroll
        for (int i = 0; i < 8; ++i)
#pragma unroll
          for (int d = 0; d < 8; ++d) acc[r][i] += a[d] * w[i][d];
      }
    }
  }
#pragma unroll
  for (int r = 0; r < 8; ++r) {
    float f[8];
#pragma unroll
    for (int i = 0; i < 8; ++i) {
      float v = acc[r][i];
      f[i] = v > 0.f ? v : __expf(v) - 1.f;   // elu
    }
    *(uint4*)(eout + (e0g + te * 8 + r) * 256 + tc * 8) = enc8(f);
  }
}

// ---------- node attention -> nag (bf16 [N][4][256]); one wave per node ----------
__global__ __launch_bounds__(256) void node_attn(
    const float* __restrict__ xf, int xlda,
    const ushort_t* __restrict__ ein, const int* __restrict__ n2e,
    const float* __restrict__ a_s, const float* __restrict__ a_edge,
    ushort_t* __restrict__ nag) {
  int t = threadIdx.x;
  int wv = t >> 6, lane = t & 63;
  long n = (long)blockIdx.x * 4 + wv;
  int d4 = lane * 4;
  float4 xv4 = *(const float4*)(xf + n * (long)xlda + d4);
  float xv[4] = {xv4.x, xv4.y, xv4.z, xv4.w};
  float eg[8][4];
#pragma unroll
  for (int k = 0; k < 8; ++k) {
    int ek = n2e[n * 8 + k];
    dec4(*(const uint2*)(ein + (long)ek * 256 + d4), eg[k]);
  }
  float ss[4], se[4][8];
#pragma unroll
  for (int h = 0; h < 4; ++h) {
    float4 as4 = *(const float4*)(a_s + h * 256 + d4);
    ss[h] = xv[0]*as4.x + xv[1]*as4.y + xv[2]*as4.z + xv[3]*as4.w;
    float4 ae4 = *(const float4*)(a_edge + h * 256 + d4);
#pragma unroll
    for (int k = 0; k < 8; ++k)
      se[h][k] = eg[k][0]*ae4.x + eg[k][1]*ae4.y + eg[k][2]*ae4.z + eg[k][3]*ae4.w;
  }
#pragma unroll
  for (int m = 1; m <= 32; m <<= 1)
#pragma unroll
    for (int h = 0; h < 4; ++h) {
      ss[h] += __shfl_xor(ss[h], m, 64);
#pragma unroll
      for (int k = 0; k < 8; ++k) se[h][k] += __shfl_xor(se[h][k], m, 64);
    }
#pragma unroll
  for (int h = 0; h < 4; ++h) {
    float sn[8], mx = -1e30f;
#pragma unroll
    for (int k = 0; k < 8; ++k) {
      float v = ss[h] + se[h][k];
      v = v > 0.f ? v : 0.2f * v;     // leaky_relu 0.2 BEFORE softmax
      sn[k] = v; mx = fmaxf(mx, v);
    }
    float sum = 0.f;
#pragma unroll
    for (int k = 0; k < 8; ++k) { sn[k] = __expf(sn[k] - mx); sum += sn[k]; }
    float inv = 1.f / sum;
    float o[4] = {0.f, 0.f, 0.f, 0.f};
#pragma unroll
    for (int k = 0; k < 8; ++k) {
      float a = sn[k] * inv;
#pragma unroll
      for (int i2 = 0; i2 < 4; ++i2) o[i2] += a * eg[k][i2];
    }
    *(uint2*)(nag + (((n << 2) + h) << 8) + d4) = enc4(o);
  }
}

// ---------- node projection: out = elu(xin@W_self + nag@W_nb) ----------
__global__ __launch_bounds__(256, 2) void node_proj(
    const float* __restrict__ xf, int xlda, const ushort_t* __restrict__ nag,
    const float* __restrict__ Wsf, const float* __restrict__ Wnb,
    float* __restrict__ outp) {
  __shared__ __align__(16) float sA[64][32];
  __shared__ __align__(16) ushort_t sN[4][64][32];
  __shared__ __align__(16) float sWt[256][32];
  int t = threadIdx.x;
  long n0 = (long)blockIdx.x * 64;
  int tc = t & 31, te = t >> 5;
  int hT = tc >> 3;
  float acc[8][8];
#pragma unroll
  for (int r = 0; r < 8; ++r)
#pragma unroll
    for (int i = 0; i < 8; ++i) acc[r][i] = 0.f;

#pragma unroll
  for (int part = 0; part < 2; ++part) {
    const float* W = part ? Wnb : Wsf;
    for (int dc = 0; dc < 8; ++dc) {
      __syncthreads();
      if (part == 0) {  // stage xin chunk (f32)
        int row = t >> 2, s = t & 3;
        const float* src = xf + (n0 + row) * (long)xlda + dc * 32 + s * 8;
        float4 v0 = *(const float4*)src, v1 = *(const float4*)(src + 4);
        int rot = (row >> 3) & 7;
        *(float4*)&sA[row][((2 * s + rot) & 7) << 2] = v0;
        *(float4*)&sA[row][((2 * s + 1 + rot) & 7) << 2] = v1;
      } else {  // stage nag chunk (bf16) for all 4 heads
#pragma unroll
        for (int i = 0; i < 4; ++i) {
          int idx = i * 256 + t;
          int hh = idx >> 8, rem = idx & 255;
          int row = rem >> 2, s = rem & 3;
          uint4 v = *(const uint4*)(nag + ((((n0 + row) << 2) + hh) << 8) + dc * 32 + s * 8);
          *(uint4*)&sN[hh][row][(((s + ((row >> 3) & 3)) & 3) << 3)] = v;
        }
      }
      stage_w_hd(W, dc, sWt, t);
      __syncthreads();
      for (int s8 = 0; s8 < 4; ++s8) {
        float w[8][8];
        read_w8(sWt, tc, s8, w);
#pragma unroll
        for (int r = 0; r < 8; ++r) {
          int row = te * 8 + r;
          float a[8];
          if (part == 0) {
            read_a8(sA, row, te & 7, s8, a);
          } else {
            dec8(*(const uint4*)&sN[hT][row][(((s8 + (te & 3)) & 3) << 3)], a);
          }
#pragma unroll
          for (int i = 0; i < 8; ++i)
#pragma unroll
            for (int d = 0; d < 8; ++d) acc[r][i] += a[d] * w[i][d];
        }
      }
    }
  }
#pragma unroll
  for (int r = 0; r < 8; ++r) {
    long nn = n0 + te * 8 + r;
    float f[8];
#pragma unroll
    for (int i = 0; i < 8; ++i) {
      float v = acc[r][i];
      f[i] = v > 0.f ? v : __expf(v) - 1.f;  // elu
    }
    float* o = outp + nn * 512 + tc * 8;
    *(float4*)o = make_float4(f[0], f[1], f[2], f[3]);
    *(float4*)(o + 4) = make_float4(f[4], f[5], f[6], f[7]);
  }
}

extern "C" void kernel_launch(void* const* d_in, const int* in_sizes, int n_in,
                              void* d_out, int out_size, void* d_ws, size_t ws_size,
                              hipStream_t stream) {
  (void)in_sizes; (void)n_in; (void)out_size; (void)ws_size;
  const float* feats  = (const float*)d_in[0];
  const float* eemb   = (const float*)d_in[1];
  const int*   adj    = (const int*)d_in[2];
  const int*   n2e    = (const int*)d_in[3];
  const float* Wp0    = (const float*)d_in[4];
  const float* Wp1    = (const float*)d_in[5];
  const float* Wep    = (const float*)d_in[6];
  const float* a_e    = (const float*)d_in[7];
  const float* a_n    = (const float*)d_in[8];
  const float* W_e    = (const float*)d_in[9];
  const float* a_s    = (const float*)d_in[10];
  const float* a_edge = (const float*)d_in[11];
  const float* W_self = (const float*)d_in[12];
  const float* W_nb   = (const float*)d_in[13];
  float* out = (float*)d_out;

  // workspace carve (~537 MB): dummy,base f32 [N][256]; edgesA/B bf16 [E][256]; nag bf16 [N][4][256]
  char* w = (char*)d_ws;
  float* dummy = (float*)w;          w += (size_t)N_NODES * 256 * 4;
  float* base  = (float*)w;          w += (size_t)N_NODES * 256 * 4;
  ushort_t* edgesA = (ushort_t*)w;   w += (size_t)N_EDGES * 256 * 2;
  ushort_t* edgesB = (ushort_t*)w;   w += (size_t)N_EDGES * 256 * 2;
  ushort_t* nag    = (ushort_t*)w;   w += (size_t)N_NODES * 4 * 256 * 2;

  // prep GEMMs (full f32)
  gemm_k<false><<<N_NODES / 64, 256, 0, stream>>>(feats, Wp0, dummy, 256);
  gemm_k<false><<<N_NODES / 64, 256, 0, stream>>>(feats, Wp1, base, 256);

  for (int mp = 0; mp < 2; ++mp) {
    gemm_k<true><<<N_EDGES / 64, 256, 0, stream>>>(
        eemb + (size_t)mp * N_EDGES * 64, Wep + (size_t)mp * 64 * 256, edgesA, 64);
    const int* adj_mp = adj + (size_t)mp * N_EDGES * 2;
    const int* n2e_mp = n2e + (size_t)mp * N_NODES * 8;
    float* xL1 = out + (size_t)mp * N_NODES * 512;  // L0 node output, stride 512

    // ----- L = 0 -----
    {
      size_t ao = (size_t)(mp * 2 + 0) * 4 * 256;
      size_t wo = (size_t)(mp * 2 + 0) * 4 * 256 * 64;
      edge_kernel<<<N_EDGES / 64, 256, 0, stream>>>(base, edgesA, edgesB, adj_mp,
                                                    a_n + ao, a_e + ao, W_e + wo);
      node_attn<<<N_NODES / 4, 256, 0, stream>>>(dummy, 256, edgesA, n2e_mp,
                                                 a_s + ao, a_edge + ao, nag);
      node_proj<<<N_NODES / 64, 256, 0, stream>>>(dummy, 256, nag, W_self + wo,
                                                  W_nb + wo,
                                                  out + (size_t)mp * N_NODES * 512);
    }
    // ----- L = 1 (edge aggregator output is dead at the last layer -> skipped) -----
    {
      size_t ao = (size_t)(mp * 2 + 1) * 4 * 256;
      size_t wo = (size_t)(mp * 2 + 1) * 4 * 256 * 64;
      node_attn<<<N_NODES / 4, 256, 0, stream>>>(xL1, 512, edgesB, n2e_mp,
                                                 a_s + ao, a_edge + ao, nag);
      node_proj<<<N_NODES / 64, 256, 0, stream>>>(xL1, 512, nag, W_self + wo,
                                                  W_nb + wo,
                                                  out + (size_t)mp * N_NODES * 512 + 256);
    }
  }
}

// Round 2
// 1925.417 us; speedup vs baseline: 2.2095x; 2.2095x over previous
//
#include <hip/hip_runtime.h>

typedef unsigned short ushort_t;
typedef unsigned int uint_t;

#define N_NODES 65536
#define N_EDGES 262144

typedef __attribute__((ext_vector_type(8))) short bf16x8;
typedef __attribute__((ext_vector_type(4))) float f32x4;

// ---------- bf16 helpers ----------
__device__ __forceinline__ ushort_t f2b(float x) {
  uint_t u = __float_as_uint(x);
  u += 0x7fffu + ((u >> 16) & 1u);  // RNE
  return (ushort_t)(u >> 16);
}
__device__ __forceinline__ void dec8(uint4 v, float* f) {
  f[0] = __uint_as_float(v.x << 16); f[1] = __uint_as_float(v.x & 0xffff0000u);
  f[2] = __uint_as_float(v.y << 16); f[3] = __uint_as_float(v.y & 0xffff0000u);
  f[4] = __uint_as_float(v.z << 16); f[5] = __uint_as_float(v.z & 0xffff0000u);
  f[6] = __uint_as_float(v.w << 16); f[7] = __uint_as_float(v.w & 0xffff0000u);
}
__device__ __forceinline__ void dec4(uint2 v, float* f) {
  f[0] = __uint_as_float(v.x << 16); f[1] = __uint_as_float(v.x & 0xffff0000u);
  f[2] = __uint_as_float(v.y << 16); f[3] = __uint_as_float(v.y & 0xffff0000u);
}
__device__ __forceinline__ uint4 enc8(const float* f) {
  uint4 v;
  v.x = (uint_t)f2b(f[0]) | ((uint_t)f2b(f[1]) << 16);
  v.y = (uint_t)f2b(f[2]) | ((uint_t)f2b(f[3]) << 16);
  v.z = (uint_t)f2b(f[4]) | ((uint_t)f2b(f[5]) << 16);
  v.w = (uint_t)f2b(f[6]) | ((uint_t)f2b(f[7]) << 16);
  return v;
}
__device__ __forceinline__ uint2 enc4(const float* f) {
  uint2 v;
  v.x = (uint_t)f2b(f[0]) | ((uint_t)f2b(f[1]) << 16);
  v.y = (uint_t)f2b(f[2]) | ((uint_t)f2b(f[3]) << 16);
  return v;
}
__device__ __forceinline__ void ld8(const float* p, float* f) {
  float4 v0 = *(const float4*)p;
  float4 v1 = *(const float4*)(p + 4);
  f[0]=v0.x; f[1]=v0.y; f[2]=v0.z; f[3]=v0.w;
  f[4]=v1.x; f[5]=v1.y; f[6]=v1.z; f[7]=v1.w;
}

#define ELUF(v) ((v) > 0.f ? (v) : __expf(v) - 1.f)

// async global->LDS, 16B per lane; lds base must be wave-uniform (lane deposits at base+lane*16)
__device__ __forceinline__ void async16(void* lds, const void* g) {
  __builtin_amdgcn_global_load_lds(
      (const __attribute__((address_space(1))) void*)g,
      (__attribute__((address_space(3))) void*)lds, 16, 0, 0);
}

// ---------- weight transpose+cvt: dst[m][n*K+k] = bf16(src[m][k*N+n]) ----------
__global__ void wt_kernel(const float* __restrict__ src, ushort_t* __restrict__ dst,
                          int K, int N) {
  long m = blockIdx.y;
  long base = m * (long)K * N;
  int tid = blockIdx.x * 256 + threadIdx.x;
  if (tid >= K * N) return;
  int k = tid % K, n = tid / K;
  dst[base + (long)n * K + k] = f2b(src[base + (long)k * N + n]);
}

// ---------- MFMA GEMM: outb[rows][256] = bf16( A_f32[rows][K] @ Wt^T ), Wt bf16 [256][K] ----------
__global__ __launch_bounds__(256, 2) void gemm_mfma(
    const float* __restrict__ A, const ushort_t* __restrict__ Wt,
    ushort_t* __restrict__ outb, int K) {
  __shared__ __align__(16) char smem[4096 + 16384];
  ushort_t (*sA)[32] = (ushort_t(*)[32])smem;           // [64][32] bf16
  ushort_t (*sB)[32] = (ushort_t(*)[32])(smem + 4096);  // [256][32] bf16
  int t = threadIdx.x, w = t >> 6, l = t & 63;
  long r0 = (long)blockIdx.x * 64;
  f32x4 zero = {0.f, 0.f, 0.f, 0.f};
  f32x4 acc[4][4];
#pragma unroll
  for (int mt = 0; mt < 4; ++mt)
#pragma unroll
    for (int nt = 0; nt < 4; ++nt) acc[mt][nt] = zero;

  for (int kc = 0; kc < K / 32; ++kc) {
    __syncthreads();
    {  // stage A (f32 -> bf16)
      int r = t >> 2, ks8 = (t & 3) * 8;
      float f[8]; ld8(A + (r0 + r) * (long)K + kc * 32 + ks8, f);
      *(uint4*)&sA[r][ks8] = enc8(f);
    }
#pragma unroll
    for (int j = 0; j < 4; ++j) {  // stage B async
      int u = (w * 4 + j) * 64 + l;
      int n = u >> 2, ks = u & 3;
      async16((char*)sB + (w * 4 + j) * 1024, Wt + (long)n * K + kc * 32 + ks * 8);
    }
    __syncthreads();
    bf16x8 af[4], bf[4];
#pragma unroll
    for (int mt = 0; mt < 4; ++mt)
      af[mt] = *(const bf16x8*)&sA[mt * 16 + (l & 15)][(l >> 4) * 8];
#pragma unroll
    for (int nt = 0; nt < 4; ++nt)
      bf[nt] = *(const bf16x8*)&sB[w * 64 + nt * 16 + (l & 15)][(l >> 4) * 8];
#pragma unroll
    for (int mt = 0; mt < 4; ++mt)
#pragma unroll
      for (int nt = 0; nt < 4; ++nt)
        acc[mt][nt] = __builtin_amdgcn_mfma_f32_16x16x32_bf16(af[mt], bf[nt], acc[mt][nt], 0, 0, 0);
  }
#pragma unroll
  for (int mt = 0; mt < 4; ++mt)
#pragma unroll
    for (int nt = 0; nt < 4; ++nt)
#pragma unroll
      for (int i = 0; i < 4; ++i) {
        long row = r0 + mt * 16 + (l >> 4) * 4 + i;
        int col = w * 64 + nt * 16 + (l & 15);
        outb[row * 256 + col] = f2b(acc[mt][nt][i]);
      }
}

// ---------- edge aggregator (L0 only), MFMA projection, wave = head ----------
__global__ __launch_bounds__(256, 2) void edge_kernel(
    const ushort_t* __restrict__ xb,   // base bf16 [N][256]
    const ushort_t* __restrict__ ein,  // bf16 [E][256]
    ushort_t* __restrict__ eout,       // bf16 [E][256]
    const int* __restrict__ ena,       // [E][2]
    const float* __restrict__ a_n, const float* __restrict__ a_e,  // [4][256]
    const ushort_t* __restrict__ Wt) { // bf16 [256 n=h*64+p][256 k]
  __shared__ __align__(16) char smem[8192 + 16384 + 4096 + 1024 + 256 + 16];
  ushort_t (*sY)[32][32] = (ushort_t(*)[32][32])smem;         // [4][32][32]
  ushort_t (*sB)[32]     = (ushort_t(*)[32])(smem + 8192);    // [256][32]
  ushort_t (*sAf)[256]   = (ushort_t(*)[256])(smem + 24576);  // [8][256]  (a_n 0-3, a_e 4-7)
  float    (*sAlp)[4][2] = (float(*)[4][2])(smem + 28672);    // [32][4][2]
  int* sIdx              = (int*)(smem + 29696);              // [64]  q*32+e
  ushort_t* sOut         = (ushort_t*)smem;                   // overlay [32][264] (16896B <= 24576)

  int t = threadIdx.x, w = t >> 6, l = t & 63;
  long e0 = (long)blockIdx.x * 32;

  if (t < 64) sIdx[(t & 1) * 32 + (t >> 1)] = ena[(e0 + (t >> 1)) * 2 + (t & 1)];
  {  // stage a_n/a_e as bf16
    int row = t >> 5, dof = (t & 31) * 8;
    const float* src = (row < 4 ? a_n + row * 256 : a_e + (row - 4) * 256) + dof;
    float f[8]; ld8(src, f);
    *(uint4*)&sAf[row][dof] = enc8(f);
  }
  __syncthreads();

  int eT = t >> 3, sT = t & 7;
  int nid0 = sIdx[eT], nid1 = sIdx[32 + eT];
  const ushort_t* pxe = ein + (e0 + eT) * 256;
  const ushort_t* px0 = xb + (long)nid0 * 256;
  const ushort_t* px1 = xb + (long)nid1 * 256;

  // ---- attention scores (direct global reads of gathered rows; 8 threads/edge) ----
  float an0[4] = {0,0,0,0}, an1[4] = {0,0,0,0}, aee[4] = {0,0,0,0};
#pragma unroll
  for (int kc = 0; kc < 8; ++kc) {
    int dof = kc * 32 + sT * 4;
    float xe[4], x0[4], x1[4];
    dec4(*(const uint2*)(pxe + dof), xe);
    dec4(*(const uint2*)(px0 + dof), x0);
    dec4(*(const uint2*)(px1 + dof), x1);
#pragma unroll
    for (int h = 0; h < 4; ++h) {
      float av[4], bv[4];
      dec4(*(const uint2*)&sAf[h][dof], av);
      dec4(*(const uint2*)&sAf[4 + h][dof], bv);
#pragma unroll
      for (int d = 0; d < 4; ++d) {
        an0[h] += x0[d] * av[d];
        an1[h] += x1[d] * av[d];
        aee[h] += xe[d] * bv[d];
      }
    }
  }
#pragma unroll
  for (int m = 1; m <= 4; m <<= 1)
#pragma unroll
    for (int h = 0; h < 4; ++h) {
      an0[h] += __shfl_xor(an0[h], m, 64);
      an1[h] += __shfl_xor(an1[h], m, 64);
      aee[h] += __shfl_xor(aee[h], m, 64);
    }
  if (sT == 0) {
#pragma unroll
    for (int h = 0; h < 4; ++h) {
      float s0 = an0[h] + aee[h]; s0 = s0 > 0.f ? s0 : 0.2f * s0;
      float s1 = an1[h] + aee[h]; s1 = s1 > 0.f ? s1 : 0.2f * s1;
      float mx = fmaxf(s0, s1);
      float g0 = __expf(s0 - mx), g1 = __expf(s1 - mx);
      float inv = 1.f / (g0 + g1);
      sAlp[eT][h][0] = g0 * inv;
      sAlp[eT][h][1] = g1 * inv;
    }
  }
  __syncthreads();
  float alp[4][2];
#pragma unroll
  for (int h = 0; h < 4; ++h) {
    alp[h][0] = sAlp[eT][h][0];
    alp[h][1] = sAlp[eT][h][1];
  }

  f32x4 zero = {0.f, 0.f, 0.f, 0.f};
  f32x4 acc[2][4];
#pragma unroll
  for (int mt = 0; mt < 2; ++mt)
#pragma unroll
    for (int nt = 0; nt < 4; ++nt) acc[mt][nt] = zero;

  int ks4 = sT * 4;
  for (int kc = 0; kc < 8; ++kc) {
    __syncthreads();
#pragma unroll
    for (int j = 0; j < 4; ++j) {  // stage Wt chunk
      int u = (w * 4 + j) * 64 + l;
      int n = u >> 2, ks = u & 3;
      async16((char*)sB + (w * 4 + j) * 1024, Wt + (long)n * 256 + kc * 32 + ks * 8);
    }
    {  // build Y = ein + a0*x0 + a1*x1 per head (bf16 into sY)
      int dof = kc * 32 + ks4;
      float xe[4], x0[4], x1[4];
      dec4(*(const uint2*)(pxe + dof), xe);
      dec4(*(const uint2*)(px0 + dof), x0);
      dec4(*(const uint2*)(px1 + dof), x1);
#pragma unroll
      for (int h = 0; h < 4; ++h) {
        float y[4];
#pragma unroll
        for (int d = 0; d < 4; ++d)
          y[d] = xe[d] + alp[h][0] * x0[d] + alp[h][1] * x1[d];
        *(uint2*)&sY[h][eT][ks4] = enc4(y);
      }
    }
    __syncthreads();
    bf16x8 af[2], bf[4];
#pragma unroll
    for (int mt = 0; mt < 2; ++mt)
      af[mt] = *(const bf16x8*)&sY[w][mt * 16 + (l & 15)][(l >> 4) * 8];
#pragma unroll
    for (int nt = 0; nt < 4; ++nt)
      bf[nt] = *(const bf16x8*)&sB[w * 64 + nt * 16 + (l & 15)][(l >> 4) * 8];
#pragma unroll
    for (int mt = 0; mt < 2; ++mt)
#pragma unroll
      for (int nt = 0; nt < 4; ++nt)
        acc[mt][nt] = __builtin_amdgcn_mfma_f32_16x16x32_bf16(af[mt], bf[nt], acc[mt][nt], 0, 0, 0);
  }
  __syncthreads();
#pragma unroll
  for (int mt = 0; mt < 2; ++mt)
#pragma unroll
    for (int nt = 0; nt < 4; ++nt)
#pragma unroll
      for (int i = 0; i < 4; ++i) {
        int row = mt * 16 + (l >> 4) * 4 + i;
        int col = w * 64 + nt * 16 + (l & 15);
        sOut[row * 264 + col] = f2b(ELUF(acc[mt][nt][i]));
      }
  __syncthreads();
#pragma unroll
  for (int j = 0; j < 4; ++j) {
    int u = t + j * 256;
    int r = u >> 5, ks = u & 31;
    *(uint4*)(eout + (e0 + r) * 256 + ks * 8) = *(const uint4*)&sOut[r * 264 + ks * 8];
  }
}

// ---------- node attention -> nag bf16 [N*4][256]; one wave per node ----------
__global__ __launch_bounds__(256) void node_attn(
    const ushort_t* __restrict__ xb,   // bf16 [N][256]
    const ushort_t* __restrict__ ein, const int* __restrict__ n2e,
    const float* __restrict__ a_s, const float* __restrict__ a_edge,
    ushort_t* __restrict__ nag) {
  int t = threadIdx.x, wv = t >> 6, lane = t & 63;
  long n = (long)blockIdx.x * 4 + wv;
  int d4 = lane * 4;
  float xv[4];
  dec4(*(const uint2*)(xb + n * 256 + d4), xv);
  float eg[8][4];
#pragma unroll
  for (int k = 0; k < 8; ++k) {
    int ek = n2e[n * 8 + k];
    dec4(*(const uint2*)(ein + (long)ek * 256 + d4), eg[k]);
  }
  float ss[4], se[4][8];
#pragma unroll
  for (int h = 0; h < 4; ++h) {
    float4 as4 = *(const float4*)(a_s + h * 256 + d4);
    ss[h] = xv[0]*as4.x + xv[1]*as4.y + xv[2]*as4.z + xv[3]*as4.w;
    float4 ae4 = *(const float4*)(a_edge + h * 256 + d4);
#pragma unroll
    for (int k = 0; k < 8; ++k)
      se[h][k] = eg[k][0]*ae4.x + eg[k][1]*ae4.y + eg[k][2]*ae4.z + eg[k][3]*ae4.w;
  }
#pragma unroll
  for (int m = 1; m <= 32; m <<= 1)
#pragma unroll
    for (int h = 0; h < 4; ++h) {
      ss[h] += __shfl_xor(ss[h], m, 64);
#pragma unroll
      for (int k = 0; k < 8; ++k) se[h][k] += __shfl_xor(se[h][k], m, 64);
    }
#pragma unroll
  for (int h = 0; h < 4; ++h) {
    float sn[8], mx = -1e30f;
#pragma unroll
    for (int k = 0; k < 8; ++k) {
      float v = ss[h] + se[h][k];
      v = v > 0.f ? v : 0.2f * v;
      sn[k] = v; mx = fmaxf(mx, v);
    }
    float sum = 0.f;
#pragma unroll
    for (int k = 0; k < 8; ++k) { sn[k] = __expf(sn[k] - mx); sum += sn[k]; }
    float inv = 1.f / sum;
    float o[4] = {0.f, 0.f, 0.f, 0.f};
#pragma unroll
    for (int k = 0; k < 8; ++k) {
      float a = sn[k] * inv;
#pragma unroll
      for (int i2 = 0; i2 < 4; ++i2) o[i2] += a * eg[k][i2];
    }
    *(uint2*)(nag + (((n << 2) + h) << 8) + d4) = enc4(o);
  }
}

// ---------- node projection: out = elu(xin@W_self + nag@W_nb), MFMA, wave = head ----------
__global__ __launch_bounds__(256, 2) void node_proj(
    const ushort_t* __restrict__ xb,   // bf16 [N][256]
    const ushort_t* __restrict__ nag,  // bf16 [N*4][256]
    const ushort_t* __restrict__ WtS, const ushort_t* __restrict__ WtN,  // [256][256]
    float* __restrict__ outp,          // f32, row stride 512
    ushort_t* __restrict__ xout) {     // bf16 [N][256] or nullptr
  __shared__ __align__(16) char smem[2048 + 8192 + 16384 + 16384];
  ushort_t (*sX)[32]  = (ushort_t(*)[32])smem;            // [32][32]
  ushort_t (*sNg)[32] = (ushort_t(*)[32])(smem + 2048);   // [128][32] (h*32+e)
  ushort_t (*sBs)[32] = (ushort_t(*)[32])(smem + 10240);  // [256][32]
  ushort_t (*sBn)[32] = (ushort_t(*)[32])(smem + 26624);  // [256][32]
  float* sOutF        = (float*)(smem + 2048);            // overlay [32][260] f32 (33280B <= 40960)
  int t = threadIdx.x, w = t >> 6, l = t & 63;
  long n0 = (long)blockIdx.x * 32;

  f32x4 zero = {0.f, 0.f, 0.f, 0.f};
  f32x4 acc[2][4];
#pragma unroll
  for (int mt = 0; mt < 2; ++mt)
#pragma unroll
    for (int nt = 0; nt < 4; ++nt) acc[mt][nt] = zero;

  for (int kc = 0; kc < 8; ++kc) {
    __syncthreads();
    if (w == 0) {
#pragma unroll
      for (int j = 0; j < 2; ++j) {
        int u = j * 64 + l;
        int r = u >> 2, ks = u & 3;
        async16((char*)sX + j * 1024, xb + (n0 + r) * 256 + kc * 32 + ks * 8);
      }
    }
#pragma unroll
    for (int j = 0; j < 2; ++j) {
      int u = (w * 2 + j) * 64 + l;
      int r = u >> 2, ks = u & 3;  // r = h*32+e
      int h = r >> 5, e = r & 31;
      async16((char*)sNg + (w * 2 + j) * 1024,
              nag + ((n0 + e) * 4 + h) * 256 + kc * 32 + ks * 8);
    }
#pragma unroll
    for (int j = 0; j < 4; ++j) {
      int u = (w * 4 + j) * 64 + l;
      int n = u >> 2, ks = u & 3;
      async16((char*)sBs + (w * 4 + j) * 1024, WtS + (long)n * 256 + kc * 32 + ks * 8);
      async16((char*)sBn + (w * 4 + j) * 1024, WtN + (long)n * 256 + kc * 32 + ks * 8);
    }
    __syncthreads();
    bf16x8 ax[2], ag[2], bs[4], bn[4];
#pragma unroll
    for (int mt = 0; mt < 2; ++mt) {
      ax[mt] = *(const bf16x8*)&sX[mt * 16 + (l & 15)][(l >> 4) * 8];
      ag[mt] = *(const bf16x8*)&sNg[w * 32 + mt * 16 + (l & 15)][(l >> 4) * 8];
    }
#pragma unroll
    for (int nt = 0; nt < 4; ++nt) {
      bs[nt] = *(const bf16x8*)&sBs[w * 64 + nt * 16 + (l & 15)][(l >> 4) * 8];
      bn[nt] = *(const bf16x8*)&sBn[w * 64 + nt * 16 + (l & 15)][(l >> 4) * 8];
    }
#pragma unroll
    for (int mt = 0; mt < 2; ++mt)
#pragma unroll
      for (int nt = 0; nt < 4; ++nt) {
        acc[mt][nt] = __builtin_amdgcn_mfma_f32_16x16x32_bf16(ax[mt], bs[nt], acc[mt][nt], 0, 0, 0);
        acc[mt][nt] = __builtin_amdgcn_mfma_f32_16x16x32_bf16(ag[mt], bn[nt], acc[mt][nt], 0, 0, 0);
      }
  }
  __syncthreads();
#pragma unroll
  for (int mt = 0; mt < 2; ++mt)
#pragma unroll
    for (int nt = 0; nt < 4; ++nt)
#pragma unroll
      for (int i = 0; i < 4; ++i) {
        int row = mt * 16 + (l >> 4) * 4 + i;
        int col = w * 64 + nt * 16 + (l & 15);
        sOutF[row * 260 + col] = ELUF(acc[mt][nt][i]);
      }
  __syncthreads();
#pragma unroll
  for (int j = 0; j < 8; ++j) {
    int u = t + j * 256;
    int r = u >> 6, ks = u & 63;
    *(float4*)(outp + (n0 + r) * 512 + ks * 4) = *(const float4*)&sOutF[r * 260 + ks * 4];
  }
  if (xout) {
#pragma unroll
    for (int j = 0; j < 8; ++j) {
      int u = t + j * 256;
      int r = u >> 6, ks = u & 63;
      const float* s = &sOutF[r * 260 + ks * 4];
      float f[4] = {s[0], s[1], s[2], s[3]};
      *(uint2*)(xout + (n0 + r) * 256 + ks * 4) = enc4(f);
    }
  }
}

extern "C" void kernel_launch(void* const* d_in, const int* in_sizes, int n_in,
                              void* d_out, int out_size, void* d_ws, size_t ws_size,
                              hipStream_t stream) {
  (void)in_sizes; (void)n_in; (void)out_size; (void)ws_size;
  const float* feats  = (const float*)d_in[0];
  const float* eemb   = (const float*)d_in[1];
  const int*   adj    = (const int*)d_in[2];
  const int*   n2e    = (const int*)d_in[3];
  const float* Wp0    = (const float*)d_in[4];
  const float* Wp1    = (const float*)d_in[5];
  const float* Wep    = (const float*)d_in[6];
  const float* a_e    = (const float*)d_in[7];
  const float* a_n    = (const float*)d_in[8];
  const float* W_e    = (const float*)d_in[9];
  const float* a_s    = (const float*)d_in[10];
  const float* a_edge = (const float*)d_in[11];
  const float* W_self = (const float*)d_in[12];
  const float* W_nb   = (const float*)d_in[13];
  float* out = (float*)d_out;

  // workspace carve (~506 MB)
  char* w = (char*)d_ws;
  ushort_t* dummy_bf = (ushort_t*)w; w += (size_t)N_NODES * 256 * 2;
  ushort_t* base_bf  = (ushort_t*)w; w += (size_t)N_NODES * 256 * 2;
  ushort_t* edgesA   = (ushort_t*)w; w += (size_t)N_EDGES * 256 * 2;
  ushort_t* edgesB   = (ushort_t*)w; w += (size_t)N_EDGES * 256 * 2;
  ushort_t* nag      = (ushort_t*)w; w += (size_t)N_NODES * 4 * 256 * 2;
  ushort_t* xl1      = (ushort_t*)w; w += (size_t)N_NODES * 256 * 2;
  ushort_t* WtP0     = (ushort_t*)w; w += 256 * 256 * 2;
  ushort_t* WtP1     = (ushort_t*)w; w += 256 * 256 * 2;
  ushort_t* WtEp     = (ushort_t*)w; w += 2 * 256 * 64 * 2;
  ushort_t* WtE      = (ushort_t*)w; w += 16 * 16384 * 2;
  ushort_t* WtS      = (ushort_t*)w; w += 16 * 16384 * 2;
  ushort_t* WtN      = (ushort_t*)w; w += 16 * 16384 * 2;

  // weight pre-transpose to bf16 Wt[n][k]
  wt_kernel<<<dim3(256, 1), 256, 0, stream>>>(Wp0, WtP0, 256, 256);
  wt_kernel<<<dim3(256, 1), 256, 0, stream>>>(Wp1, WtP1, 256, 256);
  wt_kernel<<<dim3(64, 2), 256, 0, stream>>>(Wep, WtEp, 64, 256);
  wt_kernel<<<dim3(64, 16), 256, 0, stream>>>(W_e, WtE, 256, 64);
  wt_kernel<<<dim3(64, 16), 256, 0, stream>>>(W_self, WtS, 256, 64);
  wt_kernel<<<dim3(64, 16), 256, 0, stream>>>(W_nb, WtN, 256, 64);

  // prep GEMMs
  gemm_mfma<<<N_NODES / 64, 256, 0, stream>>>(feats, WtP0, dummy_bf, 256);
  gemm_mfma<<<N_NODES / 64, 256, 0, stream>>>(feats, WtP1, base_bf, 256);

  for (int mp = 0; mp < 2; ++mp) {
    const int* adj_mp = adj + (size_t)mp * N_EDGES * 2;
    const int* n2e_mp = n2e + (size_t)mp * N_NODES * 8;
    size_t ao0 = (size_t)(mp * 2 + 0) * 1024, ao1 = (size_t)(mp * 2 + 1) * 1024;
    size_t wo0 = (size_t)(mp * 2 + 0) * 65536, wo1 = (size_t)(mp * 2 + 1) * 65536;

    gemm_mfma<<<N_EDGES / 64, 256, 0, stream>>>(
        eemb + (size_t)mp * N_EDGES * 64, WtEp + (size_t)mp * 16384, edgesA, 64);

    // L = 0
    edge_kernel<<<N_EDGES / 32, 256, 0, stream>>>(base_bf, edgesA, edgesB, adj_mp,
                                                  a_n + ao0, a_e + ao0, WtE + wo0);
    node_attn<<<N_NODES / 4, 256, 0, stream>>>(dummy_bf, edgesA, n2e_mp,
                                               a_s + ao0, a_edge + ao0, nag);
    node_proj<<<N_NODES / 32, 256, 0, stream>>>(dummy_bf, nag, WtS + wo0, WtN + wo0,
                                                out + (size_t)mp * N_NODES * 512, xl1);
    // L = 1 (last-layer edge aggregator output is dead -> skipped)
    node_attn<<<N_NODES / 4, 256, 0, stream>>>(xl1, edgesB, n2e_mp,
                                               a_s + ao1, a_edge + ao1, nag);
    node_proj<<<N_NODES / 32, 256, 0, stream>>>(xl1, nag, WtS + wo1, WtN + wo1,
                                                out + (size_t)mp * N_NODES * 512 + 256,
                                                (ushort_t*)nullptr);
  }
}